// Round 1
// baseline (131.890 us; speedup 1.0000x reference)
//
#include <hip/hip_runtime.h>

#define G_ 8
#define DIN 128
#define ACT 16
#define H1 600
#define H2 500
#define H1P 608
#define H2P 512
#define BT 128
#define NB 256
#define NCHUNK 19
#define NTHR 512

// ws offsets (bytes)
#define OFF_W2S 0
#define OFF_W1  622592
#define OFF_W2A 1867776
#define OFF_B1  1998848
#define OFF_B2S 2018304
#define OFF_W3  2020352

// LDS offsets (bytes, dynamic smem)
#define LDS_STATE 0u          // 32 KB: [nt16*4+ks][lane]*16B
#define LDS_W2S   32768u      // 2 x 32 KB: [t][ct][lane]*16B
#define LDS_H1    98304u      // 2 x 8 KB:  [t][nt][khalf*32+s32]*16B
#define LDS_W1    114688u     // 2 x 8 KB:  [ks*2+ft][lane]*16B
#define LDS_IDX   131072u
#define LDS_TOTAL 131584

typedef __attribute__((ext_vector_type(8))) short short8;
typedef __attribute__((ext_vector_type(4))) float f32x4;
typedef __attribute__((ext_vector_type(16))) float f32x16;

__device__ __forceinline__ unsigned short f2bf(float f) {
  unsigned u = __float_as_uint(f);
  unsigned r = u + 0x7fffu + ((u >> 16) & 1u);
  return (unsigned short)(r >> 16);
}

__device__ __forceinline__ short8 pack8(const float* v) {
  short8 p;
#pragma unroll
  for (int j = 0; j < 8; ++j) p[j] = (short)f2bf(v[j]);
  return p;
}

__device__ __forceinline__ void stage1k(unsigned lds_off, const void* g) {
  __builtin_amdgcn_global_load_lds(
      (const __attribute__((address_space(1))) unsigned int*)(unsigned long long)g,
      (__attribute__((address_space(3))) unsigned int*)lds_off,
      16, 0, 0);
}

__device__ __forceinline__ void stage_w2s(const char* ws, int chunk, int buf, int w, int lane) {
  const char* src = ws + OFF_W2S + (size_t)chunk * 32768;
#pragma unroll
  for (int u = 0; u < 4; ++u) {
    const int unit = w * 4 + u;
    stage1k(LDS_W2S + (unsigned)(buf * 32768 + unit * 1024), src + unit * 1024 + lane * 16);
  }
}

__device__ __forceinline__ void stage_w1(const char* ws, int g, int chunk, int buf, int w, int lane) {
  const char* src = ws + OFF_W1 + ((size_t)g * NCHUNK + chunk) * 8192;
  stage1k(LDS_W1 + (unsigned)(buf * 8192 + w * 1024), src + w * 1024 + lane * 16);
}

// ---------------- prep: build frag-linear bf16 images ----------------
__global__ __launch_bounds__(256) void prep_kernel(
    const float* __restrict__ W1, const float* __restrict__ b1,
    const float* __restrict__ W2s, const float* __restrict__ b2s,
    const float* __restrict__ W2a, const float* __restrict__ W3,
    char* __restrict__ ws)
{
  unsigned short* w2s_img = (unsigned short*)(ws + OFF_W2S);
  unsigned short* w1_img  = (unsigned short*)(ws + OFF_W1);
  unsigned short* w2a_img = (unsigned short*)(ws + OFF_W2A);
  float* b1p  = (float*)(ws + OFF_B1);
  float* b2sp = (float*)(ws + OFF_B2S);
  float* w3p  = (float*)(ws + OFF_W3);
  const int tid = blockIdx.x * blockDim.x + threadIdx.x;
  const int nthr = gridDim.x * blockDim.x;

  // W2s image: [chunk19][t2][ct16][lane64][8]
  for (int e = tid; e < 311296; e += nthr) {
    int chunk = e >> 14;
    int t  = (e >> 13) & 1;
    int ct = (e >> 9) & 15;
    int l  = (e >> 3) & 63;
    int j  = e & 7;
    int c = ct * 32 + (l & 31);
    int k = chunk * 32 + t * 16 + ((l >> 5) << 3) + j;
    float v = (c < H2 && k < H1) ? W2s[c * H1 + k] : 0.f;
    w2s_img[e] = f2bf(v);
  }
  // W1 image: [g8][chunk19][ks4][ft2][lane64][8]
  for (int e = tid; e < 622592; e += nthr) {
    int g = e / 77824;
    int rem = e - g * 77824;
    int chunk = rem >> 12;
    int rem2 = rem & 4095;
    int ks = rem2 >> 10;
    int ft = (rem2 >> 9) & 1;
    int l  = (rem2 >> 3) & 63;
    int j  = rem2 & 7;
    int f = chunk * 32 + ft * 16 + (l & 15);
    int d = ks * 32 + ((l >> 4) << 3) + j;
    float v = (f < H1) ? W1[((size_t)g * H1 + f) * DIN + d] : 0.f;
    w1_img[e] = f2bf(v);
  }
  // W2a image: [g8][ct16][lane64][8]  (k = (l>>5)*8+j in 0..15)
  for (int e = tid; e < 65536; e += nthr) {
    int g = e >> 13;
    int rem = e & 8191;
    int ct = rem >> 9;
    int l  = (rem >> 3) & 63;
    int j  = rem & 7;
    int c = ct * 32 + (l & 31);
    int a = ((l >> 5) << 3) + j;
    float v = (c < H2) ? W2a[((size_t)g * H2 + c) * ACT + a] : 0.f;
    w2a_img[e] = f2bf(v);
  }
  for (int e = tid; e < G_ * H1P; e += nthr) {
    int g = e / H1P, f = e - g * H1P;
    b1p[e] = (f < H1) ? b1[g * H1 + f] : 0.f;
  }
  for (int e = tid; e < H2P; e += nthr)
    b2sp[e] = (e < H2) ? b2s[e] : 0.f;
  for (int e = tid; e < G_ * H2P; e += nthr) {
    int g = e >> 9, c = e & 511;
    w3p[e] = (c < H2) ? W3[g * H2 + c] : 0.f;
  }
}

// ---------------- main fused kernel ----------------
__global__ __launch_bounds__(NTHR, 2) void critic_main(
    const float* __restrict__ state, const float* __restrict__ action,
    const int* __restrict__ idx, const float* __restrict__ b3,
    const char* __restrict__ ws, float* __restrict__ out)
{
  extern __shared__ char smem[];
  const int tid  = threadIdx.x;
  const int lane = tid & 63;
  const int w    = tid >> 6;
  const int s0   = blockIdx.x * BT;
  int* idx_lds = (int*)(smem + LDS_IDX);

  const unsigned short* w1img  = (const unsigned short*)(ws + OFF_W1);
  const unsigned short* w2aimg = (const unsigned short*)(ws + OFF_W2A);
  const float* b1p  = (const float*)(ws + OFF_B1);
  const float* b2sp = (const float*)(ws + OFF_B2S);
  const float* w3p  = (const float*)(ws + OFF_W3);

  // ---- phase 0: idx + state -> LDS (frag-linear bf16) ----
  if (tid < BT) idx_lds[tid] = idx[s0 + tid];
  {
    const int row = tid >> 2;
    const int cg  = tid & 3;     // = ks
    const float* sp = state + (size_t)(s0 + row) * DIN + cg * 32;
    float v[32];
#pragma unroll
    for (int u = 0; u < 8; ++u) {
      f32x4 t4 = *(const f32x4*)(sp + u * 4);
      v[u*4+0] = t4[0]; v[u*4+1] = t4[1]; v[u*4+2] = t4[2]; v[u*4+3] = t4[3];
    }
#pragma unroll
    for (int u = 0; u < 4; ++u) {
      short8 p = pack8(v + u * 8);
      const int lslot = u * 16 + (row & 15);
      const unsigned off = LDS_STATE + (unsigned)((((row >> 4) * 4 + cg) * 64 + lslot) * 16);
      *(short8*)(smem + off) = p;
    }
  }
  __syncthreads();

  const int g_lo = idx_lds[0];
  const int g_hi = idx_lds[BT - 1];

  // issue prologue stages (latency hidden under acc2 init)
  stage_w2s(ws, 0, 0, w, lane);
  stage_w1(ws, g_lo, 0, 0, w, lane);
  stage_w1(ws, g_lo, 1, 1, w, lane);

  // ---- acc2 init: h2a = W2a[g] . action, masked per game ----
  f32x16 acc2[2][4];
#pragma unroll
  for (int a = 0; a < 2; ++a)
#pragma unroll
    for (int n = 0; n < 4; ++n)
#pragma unroll
      for (int r = 0; r < 16; ++r) acc2[a][n][r] = 0.f;
  {
    short8 bact[4];
#pragma unroll
    for (int nt = 0; nt < 4; ++nt) {
      const float* ap = action + (size_t)(s0 + nt * 32 + (lane & 31)) * ACT + ((lane >> 5) << 3);
      float av[8];
      f32x4 a0 = *(const f32x4*)ap, a1 = *(const f32x4*)(ap + 4);
      av[0]=a0[0];av[1]=a0[1];av[2]=a0[2];av[3]=a0[3];
      av[4]=a1[0];av[5]=a1[1];av[6]=a1[2];av[7]=a1[3];
      bact[nt] = pack8(av);
    }
    for (int g = g_lo; g <= g_hi; ++g) {
#pragma unroll
      for (int cti = 0; cti < 2; ++cti) {
        const int ct = w * 2 + cti;
        short8 af = *(const short8*)(w2aimg + (((size_t)g * 16 + ct) * 64 + lane) * 8);
#pragma unroll
        for (int nt = 0; nt < 4; ++nt) {
          f32x16 z;
#pragma unroll
          for (int r = 0; r < 16; ++r) z[r] = 0.f;
          f32x16 t = __builtin_amdgcn_mfma_f32_32x32x16_bf16(af, bact[nt], z, 0, 0, 0);
          const bool p = (idx_lds[nt * 32 + (lane & 31)] == g);
#pragma unroll
          for (int r = 0; r < 16; ++r) acc2[cti][nt][r] = p ? t[r] : acc2[cti][nt][r];
        }
      }
    }
  }

  asm volatile("s_waitcnt vmcnt(0)" ::: "memory");
  __syncthreads();

  // layer-1 for chunk c (32 features) -> h1 slab [buf]; per-game masked
  auto layer1 = [&](int c, int buf) {
    for (int g = g_lo; g <= g_hi; ++g) {
      f32x4 a1acc[2];
#pragma unroll
      for (int ft = 0; ft < 2; ++ft) { a1acc[ft][0]=0.f;a1acc[ft][1]=0.f;a1acc[ft][2]=0.f;a1acc[ft][3]=0.f; }
#pragma unroll
      for (int ks = 0; ks < 4; ++ks) {
        short8 bs = *(const short8*)(smem + LDS_STATE + (unsigned)(((w * 4 + ks) * 64 + lane) * 16));
#pragma unroll
        for (int ft = 0; ft < 2; ++ft) {
          short8 aw;
          if (g == g_lo)
            aw = *(const short8*)(smem + LDS_W1 + (unsigned)(buf * 8192 + (ks * 2 + ft) * 1024 + lane * 16));
          else
            aw = *(const short8*)(w1img + (((size_t)g * NCHUNK + c) * 8 + ks * 2 + ft) * 512 + lane * 8);
          a1acc[ft] = __builtin_amdgcn_mfma_f32_16x16x32_bf16(aw, bs, a1acc[ft], 0, 0, 0);
        }
      }
      const int sl = w * 16 + (lane & 15);
      if (idx_lds[sl] == g) {
        const int kloc  = (lane >> 4) << 2;          // 0,4,8,12
        const int khalf = kloc >> 3;
        const int j0    = kloc & 7;
        const int s32   = (w & 1) * 16 + (lane & 15);
        const int nt    = w >> 1;
#pragma unroll
        for (int ft = 0; ft < 2; ++ft) {
          const int fglob = c * 32 + ft * 16 + kloc;
          unsigned long long pkv = 0ull;
#pragma unroll
          for (int r = 0; r < 4; ++r) {
            float hv = a1acc[ft][r] + b1p[g * H1P + fglob + r];
            hv = fmaxf(hv, 0.f);
            pkv |= ((unsigned long long)f2bf(hv)) << (16 * r);
          }
          const unsigned off = LDS_H1 + (unsigned)(buf * 8192 + ft * 4096 + nt * 1024 + (khalf * 32 + s32) * 16 + j0 * 2);
          *(unsigned long long*)(smem + off) = pkv;
        }
      }
    }
  };

  layer1(0, 0);
  __syncthreads();

  // ---- main pipelined loop over 19 chunks ----
  for (int i = 0; i < NCHUNK; ++i) {
    const int cur = i & 1, nxt = cur ^ 1;
    if (i + 1 < NCHUNK) stage_w2s(ws, i + 1, nxt, w, lane);
    if (i + 2 < NCHUNK) stage_w1(ws, g_lo, i + 2, cur, w, lane);

    // layer-2: 2 k-steps of chunk i
#pragma unroll
    for (int t = 0; t < 2; ++t) {
      short8 bf[4];
#pragma unroll
      for (int nt = 0; nt < 4; ++nt)
        bf[nt] = *(const short8*)(smem + LDS_H1 + (unsigned)(cur * 8192 + t * 4096 + nt * 1024 + lane * 16));
#pragma unroll
      for (int cti = 0; cti < 2; ++cti) {
        short8 af = *(const short8*)(smem + LDS_W2S + (unsigned)(cur * 32768 + t * 16384 + (w * 2 + cti) * 1024 + lane * 16));
#pragma unroll
        for (int nt = 0; nt < 4; ++nt)
          acc2[cti][nt] = __builtin_amdgcn_mfma_f32_32x32x16_bf16(af, bf[nt], acc2[cti][nt], 0, 0, 0);
      }
    }

    if (i + 1 < NCHUNK) layer1(i + 1, nxt);
    asm volatile("s_waitcnt vmcnt(0)" ::: "memory");
    __syncthreads();
  }

  // ---- epilogue: bias + relu + W3[g] dot + reduce + atomicAdd ----
  float qp[4] = {0.f, 0.f, 0.f, 0.f};
#pragma unroll
  for (int cti = 0; cti < 2; ++cti) {
    const int ctbase = (w * 2 + cti) * 32 + ((lane >> 5) << 2);
#pragma unroll
    for (int r = 0; r < 16; ++r) {
      const int c = ctbase + (r & 3) + ((r >> 2) << 3);
      const float b2v = b2sp[c];
#pragma unroll
      for (int nt = 0; nt < 4; ++nt) {
        const int gs = idx_lds[nt * 32 + (lane & 31)];
        float v2 = acc2[cti][nt][r] + b2v;
        v2 = fmaxf(v2, 0.f);
        qp[nt] += v2 * w3p[gs * H2P + c];
      }
    }
  }
#pragma unroll
  for (int nt = 0; nt < 4; ++nt) {
    float v2 = qp[nt];
    v2 += __shfl_xor(v2, 32, 64);
    if (lane < 32) {
      const int sl = nt * 32 + lane;
      float add = v2;
      if (w == 0) add += b3[idx_lds[sl]];
      atomicAdd(out + s0 + sl, add);
    }
  }
}

extern "C" void kernel_launch(void* const* d_in, const int* in_sizes, int n_in,
                              void* d_out, int out_size, void* d_ws, size_t ws_size,
                              hipStream_t stream) {
  const float* state  = (const float*)d_in[0];
  const float* action = (const float*)d_in[1];
  const int*   idx    = (const int*)d_in[2];
  const float* W1     = (const float*)d_in[3];
  const float* b1     = (const float*)d_in[4];
  const float* W2s    = (const float*)d_in[5];
  const float* b2s    = (const float*)d_in[6];
  const float* W2a    = (const float*)d_in[7];
  const float* W3     = (const float*)d_in[8];
  const float* b3     = (const float*)d_in[9];
  float* out = (float*)d_out;
  char* ws = (char*)d_ws;

  (void)hipFuncSetAttribute((const void*)critic_main,
                            hipFuncAttributeMaxDynamicSharedMemorySize, LDS_TOTAL);
  hipMemsetAsync(d_out, 0, 32768 * sizeof(float), stream);
  hipLaunchKernelGGL(prep_kernel, dim3(1024), dim3(256), 0, stream,
                     W1, b1, W2s, b2s, W2a, W3, ws);
  hipLaunchKernelGGL(critic_main, dim3(NB), dim3(NTHR), LDS_TOTAL, stream,
                     state, action, idx, b3, ws, out);
}